// Round 18
// baseline (1310.552 us; speedup 1.0000x reference)
//
#include <hip/hip_runtime.h>

#define HID  256
#define DDYN 5
#define NS   27
#define TS   365
#define BS   4            // batch rows per block
#define NW   16           // waves per block
#define UPW  16           // hidden units owned per wave
#define NTILE 3           // 16-col MFMA tiles per wave (one per gate)
#define AR   5            // Abuf rows: 0..3 = h batch rows, 4 = permanent zeros
#define SA   272          // Abuf row stride in bf16 elems (8-bank shift/row)

typedef short short8 __attribute__((ext_vector_type(8)));
typedef float f32x4  __attribute__((ext_vector_type(4)));

__device__ __forceinline__ unsigned short f2bf(float f) {
    union { float f; unsigned u; } v; v.f = f;
    unsigned r = v.u + 0x7FFFu + ((v.u >> 16) & 1u);   // RNE
    return (unsigned short)(r >> 16);
}
__device__ __forceinline__ float bf2f(unsigned short s) {
    union { unsigned u; float f; } v; v.u = ((unsigned)s) << 16;
    return v.f;
}
__device__ __forceinline__ float bf2f_s(short s) {
    union { unsigned u; float f; } v; v.u = ((unsigned)(unsigned short)s) << 16;
    return v.f;
}
__device__ __forceinline__ float fsig(float x) {
    float e = __builtin_amdgcn_exp2f(-1.4426950408889634f * x);
    return __builtin_amdgcn_rcpf(1.0f + e);
}
__device__ __forceinline__ float ftanh(float x) {
    float e = __builtin_amdgcn_exp2f(2.8853900817779268f * x);
    return 1.0f - 2.0f * __builtin_amdgcn_rcpf(1.0f + e);
}

// History: R7 736 FAIL (exec-mask) -> R8 615 WIN (zero-row broadcast) ->
// R9 617 NEUTRAL (3-reg diet; WRITE 174MB unchanged) -> R10 695 FAIL
// (512thr/256reg: VGPR_Count=128, WRITE 162MB persisted, occupancy 23% ->
// spill latency lost its TLP cover; reverted per pre-registration).
//
// Model v3 (from R9/R10 contrast): the binding resource is LDS wave-
// instruction issue (~12 cyc/b128, m134), ~2600-3000 cyc/CU/step = ~64% of
// the 4050-cyc step at 20 LDS instrs/wave/step. R8's byte-cut (not
// instr-cut) gaining only 4% confirms fixed per-instruction cost dominates.
// VMEM pipe is idle (HBM 5%).
//
// R11 (fifth submission; four rounds lost to GPU timeout): LDS instrs
// 20 -> 15 per wave per step (issue-weighted ~-25%).
//  a) WxL deleted: phase-B gate weights + biases read from GLOBAL f32
//     (L1-hot, 48 rows x 20 B per CU; 4 lanes share each address). Removes
//     3 ds_read_b128/wave/step + ~18 bf2f VALU/thread (f32 needs no unpack).
//     The per-chunk "memory" clobbers force re-load each step (no hoisting
//     into 18 live regs -> no new spill pressure); loads are L1-hot.
//  b) ig folded into pre at slot 192+lane; phase-B reads written as pairs
//     {0,64},{128,192} -> 2x ds_read2_b32 (4 b32 reads -> 2 instrs;
//     offsets 256 B apart fit the 8-bit x4 offset fields).
// Register discipline unchanged: full K-unroll (Bf static), per-chunk
// clobbers bound A-frag prefetch, no x-MFMA in loop.
// Tripwire: if WRITE_SIZE > 250 MB or dur regresses -> revert (a), keep (b).
// R12 (pre-scoped, all branches): shfl-based acc->phaseB exchange (the
// (n,reg)->(up,r) transpose is an intra-wave 4-lane-granular exchange);
// ledger 15 -> 10 and removes the store->drain->read serial chain.
__global__ __launch_bounds__(1024)
void ealstm_kernel(const float* __restrict__ x_dyn,  const float* __restrict__ x_stat,
                   const float* __restrict__ W_i,    const float* __restrict__ b_i,
                   const float* __restrict__ W_f,    const float* __restrict__ b_f,
                   const float* __restrict__ W_g,    const float* __restrict__ b_g,
                   const float* __restrict__ W_o,    const float* __restrict__ b_o,
                   const float* __restrict__ W_head, const float* __restrict__ b_head,
                   float* __restrict__ out)
{
    // LDS: 5440 + 16384 + 23360 + 432 = 45616 B
    __shared__ __align__(16) unsigned short Abuf[2][AR * SA]; // h rows 0..3 + zero row 4, double-buffered
    __shared__ __align__(16) float          pre[NW * 256];    // per wave: gates 0-191, ig 192-255
    __shared__ __align__(16) unsigned short xcA[TS * 4 * 8];  // per (t,row): x[0..4], 1.0, 0, 0 (bf16)
    __shared__ __align__(16) float          xst[BS * NS];

    const int tid  = threadIdx.x;
    const int bid  = blockIdx.x;
    const int b0   = bid * BS;
    const int lane = tid & 63;
    const int wv   = tid >> 6;        // wave 0..15
    const int q    = lane >> 4;       // quad 0..3 (MFMA K-group)
    const int n    = lane & 15;       // MFMA col-in-tile / A row
    const int up   = lane >> 2;       // unit-local 0..15 (phase B)
    const int r    = lane & 3;        // batch row 0..3 (phase B)
    const int u    = wv * UPW + up;   // owned hidden unit (phase B)
    const int woff = u * (DDYN + HID); // x-part weight row offset (loop-invariant)

    // ---- init LDS ----
    for (int i = tid; i < 2 * AR * SA / 2; i += 1024)
        ((unsigned int*)Abuf)[i] = 0u;                 // zero both A buffers (h0 = 0; row 4 stays 0 forever)
    for (int i = tid; i < BS * NS; i += 1024)
        xst[i] = x_stat[(b0 + i / NS) * NS + (i % NS)];
    for (int i = tid; i < TS * BS; i += 1024) {        // x rows, 16B-aligned per (t,row)
        int t = i >> 2, rr = i & 3;
        const float* xp = x_dyn + ((size_t)(b0 + rr) * TS + t) * DDYN;
        unsigned short* dst = &xcA[(unsigned)i * 8];
        #pragma unroll
        for (int d = 0; d < DDYN; d++) dst[d] = f2bf(xp[d]);
        dst[5] = 0x3F80; dst[6] = 0; dst[7] = 0;
    }

    // ---- persistent B fragments: 3 tiles x 8 K-chunks x 4 VGPR = 96 regs ----
    short8 Bf[NTILE][8];
    #pragma unroll
    for (int j = 0; j < NTILE; j++) {
        int urow = wv * UPW + n;           // weight row (hidden unit), gate j
        const float* Wg = j == 0 ? W_f : (j == 1 ? W_g : W_o);
        const float* wrow = Wg + urow * (DDYN + HID) + DDYN;   // skip x-part
        #pragma unroll
        for (int c = 0; c < 8; c++) {
            int k0 = c * 32 + q * 8;
            short8 fr;
            #pragma unroll
            for (int e = 0; e < 8; e++) fr[e] = (short)f2bf(wrow[k0 + e]);
            Bf[j][c] = fr;
        }
    }
    __syncthreads();

    // ---- i_gate for this thread's (unit u, row r) -> pre slot 192+lane ----
    float cst = 0.f;
    {
        float a = b_i[u];
        for (int s = 0; s < NS; s++)
            a += xst[r * NS + s] * W_i[u * NS + s];
        pre[wv * 256 + 192 + lane] = fsig(a);   // same thread writes & reads this slot
    }
    __syncthreads();

    const int aoff  = (n < 4 ? n : 4) * SA;   // rows 4..15 -> shared zero row (LDS broadcast)
    const int pbase = wv * 256 + lane;        // phase-B read base (gate 0)

    // One LSTM step: PA/PB are compile-time LDS bases after macro expansion.
#define STEP(PA, PB, T)                                                        \
    {                                                                          \
        f32x4 acc[NTILE];                                                      \
        _Pragma("unroll")                                                      \
        for (int j = 0; j < NTILE; j++) acc[j] = (f32x4){0.f, 0.f, 0.f, 0.f}; \
        _Pragma("unroll")                                                      \
        for (int c = 0; c < 8; c++) {                                          \
            short8 a = *(const short8*)&(PA)[aoff + c * 32 + q * 8];           \
            _Pragma("unroll")                                                  \
            for (int j = 0; j < NTILE; j++)                                    \
                acc[j] = __builtin_amdgcn_mfma_f32_16x16x32_bf16(              \
                    a, Bf[j][c], acc[j], 0, 0, 0);                             \
            __asm__ volatile("" ::: "memory");                                 \
        }                                                                      \
        if (q == 0) {                                                          \
            _Pragma("unroll")                                                  \
            for (int j = 0; j < NTILE; j++)                                    \
                *(f32x4*)&pre[wv * 256 + j * 64 + n * 4] = acc[j];             \
        }                                                                      \
        __asm__ volatile("s_waitcnt lgkmcnt(0)" ::: "memory");                 \
        {                                                                      \
            /* paired b32 reads -> 2x ds_read2_b32 */                          \
            float pA0 = pre[pbase];                                            \
            float pA1 = pre[pbase + 64];                                       \
            float pA2 = pre[pbase + 128];                                      \
            float igv = pre[pbase + 192];                                      \
            short8 xv = *(const short8*)&xcA[(unsigned)((T) * 4 + r) * 8];     \
            /* x-part from GLOBAL f32 (L1-hot, off the LDS pipe) */            \
            float pf = pA0 + b_f[u];                                           \
            float pg = pA1 + b_g[u];                                           \
            float po = pA2 + b_o[u];                                           \
            _Pragma("unroll")                                                  \
            for (int d = 0; d < DDYN; d++) {                                   \
                float xd = bf2f_s(xv[d]);                                      \
                pf += xd * W_f[woff + d];                                      \
                pg += xd * W_g[woff + d];                                      \
                po += xd * W_o[woff + d];                                      \
            }                                                                  \
            float f  = fsig(pf);                                               \
            float g_ = ftanh(pg);                                              \
            float o  = fsig(po);                                               \
            cst = f * cst + igv * g_;                                          \
            float h = o * ftanh(cst);                                          \
            (PB)[r * SA + u] = f2bf(h);                                        \
        }                                                                      \
        __syncthreads();                                                       \
    }

    // ---- time loop, unrolled x2: t=0..363 as 182 pairs, then tail t=364 ----
    {
        unsigned short* const A0 = &Abuf[0][0];
        unsigned short* const A1 = &Abuf[1][0];
        for (int tp = 0; tp < 182; tp++) {
            const int t0 = tp * 2;
            STEP(A0, A1, t0);        // even step: read buf0, write buf1
            STEP(A1, A0, t0 + 1);    // odd  step: read buf1, write buf0
        }
        STEP(A0, A1, 364);           // tail: final h lands in buffer 1
    }
#undef STEP

    // ---- head: out[b] = h . W_head + b_head (TS odd -> final h in buffer 1) ----
    {
        float h = bf2f(Abuf[1][r * SA + u]);
        pre[u * 4 + r] = h * W_head[u];
    }
    __syncthreads();
    if (tid < 64) {
        f32x4 s = *(const f32x4*)&pre[tid * 4];
        #pragma unroll
        for (int k = 1; k < 4; k++) {
            f32x4 v = *(const f32x4*)&pre[(tid + k * 64) * 4];
            #pragma unroll
            for (int rr = 0; rr < BS; rr++) s[rr] += v[rr];
        }
        #pragma unroll
        for (int off = 32; off > 0; off >>= 1)
            #pragma unroll
            for (int rr = 0; rr < BS; rr++) s[rr] += __shfl_down(s[rr], off, 64);
        if (tid == 0) {
            float bh = b_head[0];
            #pragma unroll
            for (int rr = 0; rr < BS; rr++) out[b0 + rr] = s[rr] + bh;
        }
    }
}

extern "C" void kernel_launch(void* const* d_in, const int* in_sizes, int n_in,
                              void* d_out, int out_size, void* d_ws, size_t ws_size,
                              hipStream_t stream) {
    ealstm_kernel<<<256, 1024, 0, stream>>>(
        (const float*)d_in[0],  (const float*)d_in[1],  (const float*)d_in[2],
        (const float*)d_in[3],  (const float*)d_in[4],  (const float*)d_in[5],
        (const float*)d_in[6],  (const float*)d_in[7],  (const float*)d_in[8],
        (const float*)d_in[9],  (const float*)d_in[10], (const float*)d_in[11],
        (float*)d_out);
}

// Round 20
// 617.423 us; speedup vs baseline: 2.1226x; 2.1226x over previous
//
#include <hip/hip_runtime.h>

#define HID  256
#define DDYN 5
#define NS   27
#define TS   365
#define BS   4            // batch rows per block
#define NW   16           // waves per block
#define UPW  16           // hidden units owned per wave
#define NTILE 3           // 16-col MFMA tiles per wave (one per gate)
#define AR   5            // Abuf rows: 0..3 = h batch rows, 4 = permanent zeros
#define SA   272          // Abuf row stride in bf16 elems (8-bank shift/row)
#define G3   768          // 3 gates * 256

typedef short short8 __attribute__((ext_vector_type(8)));
typedef float f32x4  __attribute__((ext_vector_type(4)));

__device__ __forceinline__ unsigned short f2bf(float f) {
    union { float f; unsigned u; } v; v.f = f;
    unsigned r = v.u + 0x7FFFu + ((v.u >> 16) & 1u);   // RNE
    return (unsigned short)(r >> 16);
}
__device__ __forceinline__ float bf2f(unsigned short s) {
    union { unsigned u; float f; } v; v.u = ((unsigned)s) << 16;
    return v.f;
}
__device__ __forceinline__ float bf2f_s(short s) {
    union { unsigned u; float f; } v; v.u = ((unsigned)(unsigned short)s) << 16;
    return v.f;
}
__device__ __forceinline__ float fsig(float x) {
    float e = __builtin_amdgcn_exp2f(-1.4426950408889634f * x);
    return __builtin_amdgcn_rcpf(1.0f + e);
}
__device__ __forceinline__ float ftanh(float x) {
    float e = __builtin_amdgcn_exp2f(2.8853900817779268f * x);
    return 1.0f - 2.0f * __builtin_amdgcn_rcpf(1.0f + e);
}

// History: R7 736 FAIL (exec-mask) -> R8 615 WIN (zero-row broadcast) ->
// R9 617 NEUTRAL (diet) -> R10 695 FAIL (512thr restructure) ->
// R11 1310 FAIL: phase-B weights from GLOBAL put ~18 divergent VMEM loads
// on the barrier-locked critical path (no cross-wave hiding; vmcnt chains
// serialize; clobbers block batching). VALUBusy 45->17.6, step 4050->8600cyc.
// LESSON: LDS->VMEM moves only for prefetchable loads, never for
// barrier-phase-locked consumption. Tripwire fired -> revert (a), keep (b).
//
// R12 (re-submitted; round lost to GPU timeout) = R9 structure (WxL bf16 in
// LDS, bit-identical arithmetic) + (b): ig folded into pre slot 192+lane ->
// phase-B scalar reads pair as 2x ds_read2_b32 ({0,+64},{+128,+192};
// 256 B apart fits the x4 8-bit offset field).
// Ledger: 20 -> 18 LDS instrs/wave/step.
// Register discipline: full K-unroll (Bf static), per-chunk clobbers bound
// A-frag prefetch depth, no x-MFMA in loop. 64V+64A at the 128-reg cap.
// Next (pre-registered): neutral -> R13 = i8 16x16x64 recurrent MFMA
// (A-reads 8->4, MFMA residency halved); <595 -> continue diet.
__global__ __launch_bounds__(1024)
void ealstm_kernel(const float* __restrict__ x_dyn,  const float* __restrict__ x_stat,
                   const float* __restrict__ W_i,    const float* __restrict__ b_i,
                   const float* __restrict__ W_f,    const float* __restrict__ b_f,
                   const float* __restrict__ W_g,    const float* __restrict__ b_g,
                   const float* __restrict__ W_o,    const float* __restrict__ b_o,
                   const float* __restrict__ W_head, const float* __restrict__ b_head,
                   float* __restrict__ out)
{
    // LDS: 5440 + 16384 + 12288 + 23360 + 432 = 57904 B
    __shared__ __align__(16) unsigned short Abuf[2][AR * SA]; // h rows 0..3 + zero row 4, double-buffered
    __shared__ __align__(16) float          pre[NW * 256];    // per wave: gates 0-191, ig 192-255
    __shared__ __align__(16) unsigned short WxL[G3 * 8];      // per col: Wx[0..4], bias, 0, 0 (bf16)
    __shared__ __align__(16) unsigned short xcA[TS * 4 * 8];  // per (t,row): x[0..4], 1.0, 0, 0 (bf16)
    __shared__ __align__(16) float          xst[BS * NS];

    const int tid  = threadIdx.x;
    const int bid  = blockIdx.x;
    const int b0   = bid * BS;
    const int lane = tid & 63;
    const int wv   = tid >> 6;        // wave 0..15
    const int q    = lane >> 4;       // quad 0..3 (MFMA K-group)
    const int n    = lane & 15;       // MFMA col-in-tile / A row
    const int up   = lane >> 2;       // unit-local 0..15 (phase B)
    const int r    = lane & 3;        // batch row 0..3 (phase B)
    const int u    = wv * UPW + up;   // owned hidden unit (phase B)

    // ---- init LDS ----
    for (int i = tid; i < 2 * AR * SA / 2; i += 1024)
        ((unsigned int*)Abuf)[i] = 0u;                 // zero both A buffers (h0 = 0; row 4 stays 0 forever)
    for (int i = tid; i < BS * NS; i += 1024)
        xst[i] = x_stat[(b0 + i / NS) * NS + (i % NS)];
    for (int i = tid; i < TS * BS; i += 1024) {        // x rows, 16B-aligned per (t,row)
        int t = i >> 2, rr = i & 3;
        const float* xp = x_dyn + ((size_t)(b0 + rr) * TS + t) * DDYN;
        unsigned short* dst = &xcA[(unsigned)i * 8];
        #pragma unroll
        for (int d = 0; d < DDYN; d++) dst[d] = f2bf(xp[d]);
        dst[5] = 0x3F80; dst[6] = 0; dst[7] = 0;
    }
    if (tid < G3) {
        int col = tid;
        int gate = col >> 8, hc = col & 255;
        const float* Wg = gate == 0 ? W_f : (gate == 1 ? W_g : W_o);
        const float* bg = gate == 0 ? b_f : (gate == 1 ? b_g : b_o);
        #pragma unroll
        for (int d = 0; d < DDYN; d++) WxL[col * 8 + d] = f2bf(Wg[hc * (DDYN + HID) + d]);
        WxL[col * 8 + 5] = f2bf(bg[hc]);
        WxL[col * 8 + 6] = 0; WxL[col * 8 + 7] = 0;
    }

    // ---- persistent B fragments: 3 tiles x 8 K-chunks x 4 VGPR = 96 regs ----
    short8 Bf[NTILE][8];
    #pragma unroll
    for (int j = 0; j < NTILE; j++) {
        int urow = wv * UPW + n;           // weight row (hidden unit), gate j
        const float* Wg = j == 0 ? W_f : (j == 1 ? W_g : W_o);
        const float* wrow = Wg + urow * (DDYN + HID) + DDYN;   // skip x-part
        #pragma unroll
        for (int c = 0; c < 8; c++) {
            int k0 = c * 32 + q * 8;
            short8 fr;
            #pragma unroll
            for (int e = 0; e < 8; e++) fr[e] = (short)f2bf(wrow[k0 + e]);
            Bf[j][c] = fr;
        }
    }
    __syncthreads();

    // ---- i_gate for this thread's (unit u, row r) -> pre slot 192+lane ----
    float cst = 0.f;
    {
        float a = b_i[u];
        for (int s = 0; s < NS; s++)
            a += xst[r * NS + s] * W_i[u * NS + s];
        pre[wv * 256 + 192 + lane] = fsig(a);   // same thread writes & reads this slot
    }
    __syncthreads();

    const int aoff  = (n < 4 ? n : 4) * SA;   // rows 4..15 -> shared zero row (LDS broadcast)
    const int pbase = wv * 256 + lane;        // phase-B read base (gate 0)

    // One LSTM step: PA/PB are compile-time LDS bases after macro expansion.
#define STEP(PA, PB, T)                                                        \
    {                                                                          \
        f32x4 acc[NTILE];                                                      \
        _Pragma("unroll")                                                      \
        for (int j = 0; j < NTILE; j++) acc[j] = (f32x4){0.f, 0.f, 0.f, 0.f}; \
        _Pragma("unroll")                                                      \
        for (int c = 0; c < 8; c++) {                                          \
            short8 a = *(const short8*)&(PA)[aoff + c * 32 + q * 8];           \
            _Pragma("unroll")                                                  \
            for (int j = 0; j < NTILE; j++)                                    \
                acc[j] = __builtin_amdgcn_mfma_f32_16x16x32_bf16(              \
                    a, Bf[j][c], acc[j], 0, 0, 0);                             \
            __asm__ volatile("" ::: "memory");                                 \
        }                                                                      \
        if (q == 0) {                                                          \
            _Pragma("unroll")                                                  \
            for (int j = 0; j < NTILE; j++)                                    \
                *(f32x4*)&pre[wv * 256 + j * 64 + n * 4] = acc[j];             \
        }                                                                      \
        __asm__ volatile("s_waitcnt lgkmcnt(0)" ::: "memory");                 \
        {                                                                      \
            /* paired b32 reads -> 2x ds_read2_b32 */                          \
            float pA0 = pre[pbase];                                            \
            float pA1 = pre[pbase + 64];                                       \
            float pA2 = pre[pbase + 128];                                      \
            float igv = pre[pbase + 192];                                      \
            short8 xv = *(const short8*)&xcA[(unsigned)((T) * 4 + r) * 8];     \
            short8 wf = *(const short8*)&WxL[(u)        * 8];                  \
            short8 wg = *(const short8*)&WxL[(256 + u)  * 8];                  \
            short8 wo = *(const short8*)&WxL[(512 + u)  * 8];                  \
            float pf = pA0 + bf2f_s(wf[5]);                                    \
            float pg = pA1 + bf2f_s(wg[5]);                                    \
            float po = pA2 + bf2f_s(wo[5]);                                    \
            _Pragma("unroll")                                                  \
            for (int d = 0; d < DDYN; d++) {                                   \
                float xd = bf2f_s(xv[d]);                                      \
                pf += xd * bf2f_s(wf[d]);                                      \
                pg += xd * bf2f_s(wg[d]);                                      \
                po += xd * bf2f_s(wo[d]);                                      \
            }                                                                  \
            float f  = fsig(pf);                                               \
            float g_ = ftanh(pg);                                              \
            float o  = fsig(po);                                               \
            cst = f * cst + igv * g_;                                          \
            float h = o * ftanh(cst);                                          \
            (PB)[r * SA + u] = f2bf(h);                                        \
        }                                                                      \
        __syncthreads();                                                       \
    }

    // ---- time loop, unrolled x2: t=0..363 as 182 pairs, then tail t=364 ----
    {
        unsigned short* const A0 = &Abuf[0][0];
        unsigned short* const A1 = &Abuf[1][0];
        for (int tp = 0; tp < 182; tp++) {
            const int t0 = tp * 2;
            STEP(A0, A1, t0);        // even step: read buf0, write buf1
            STEP(A1, A0, t0 + 1);    // odd  step: read buf1, write buf0
        }
        STEP(A0, A1, 364);           // tail: final h lands in buffer 1
    }
#undef STEP

    // ---- head: out[b] = h . W_head + b_head (TS odd -> final h in buffer 1) ----
    {
        float h = bf2f(Abuf[1][r * SA + u]);
        pre[u * 4 + r] = h * W_head[u];
    }
    __syncthreads();
    if (tid < 64) {
        f32x4 s = *(const f32x4*)&pre[tid * 4];
        #pragma unroll
        for (int k = 1; k < 4; k++) {
            f32x4 v = *(const f32x4*)&pre[(tid + k * 64) * 4];
            #pragma unroll
            for (int rr = 0; rr < BS; rr++) s[rr] += v[rr];
        }
        #pragma unroll
        for (int off = 32; off > 0; off >>= 1)
            #pragma unroll
            for (int rr = 0; rr < BS; rr++) s[rr] += __shfl_down(s[rr], off, 64);
        if (tid == 0) {
            float bh = b_head[0];
            #pragma unroll
            for (int rr = 0; rr < BS; rr++) out[b0 + rr] = s[rr] + bh;
        }
    }
}

extern "C" void kernel_launch(void* const* d_in, const int* in_sizes, int n_in,
                              void* d_out, int out_size, void* d_ws, size_t ws_size,
                              hipStream_t stream) {
    ealstm_kernel<<<256, 1024, 0, stream>>>(
        (const float*)d_in[0],  (const float*)d_in[1],  (const float*)d_in[2],
        (const float*)d_in[3],  (const float*)d_in[4],  (const float*)d_in[5],
        (const float*)d_in[6],  (const float*)d_in[7],  (const float*)d_in[8],
        (const float*)d_in[9],  (const float*)d_in[10], (const float*)d_in[11],
        (float*)d_out);
}

// Round 25
// 590.992 us; speedup vs baseline: 2.2175x; 1.0447x over previous
//
#include <hip/hip_runtime.h>

#define HID  256
#define DDYN 5
#define NS   27
#define TS   365
#define BS   4            // batch rows per block
#define NW   16           // waves per block
#define UPW  16           // hidden units owned per wave
#define NTILE 3           // 16-col MFMA tiles per wave (one per gate)
#define AR   5            // Abuf rows: slots 0..3 = batch rows, 4 = permanent zeros
#define SA   272          // Abuf row stride in bf16 elems (8-bank shift/row)
#define G3   768          // 3 gates * 256

typedef short short8 __attribute__((ext_vector_type(8)));
typedef float f32x4  __attribute__((ext_vector_type(4)));

__device__ __forceinline__ unsigned short f2bf(float f) {
    union { float f; unsigned u; } v; v.f = f;
    unsigned r = v.u + 0x7FFFu + ((v.u >> 16) & 1u);   // RNE
    return (unsigned short)(r >> 16);
}
__device__ __forceinline__ float bf2f(unsigned short s) {
    union { unsigned u; float f; } v; v.u = ((unsigned)s) << 16;
    return v.f;
}
__device__ __forceinline__ float bf2f_s(short s) {
    union { unsigned u; float f; } v; v.u = ((unsigned)(unsigned short)s) << 16;
    return v.f;
}
__device__ __forceinline__ float fsig(float x) {
    float e = __builtin_amdgcn_exp2f(-1.4426950408889634f * x);
    return __builtin_amdgcn_rcpf(1.0f + e);
}
__device__ __forceinline__ float ftanh(float x) {
    float e = __builtin_amdgcn_exp2f(2.8853900817779268f * x);
    return 1.0f - 2.0f * __builtin_amdgcn_rcpf(1.0f + e);
}

// History: R7 736 FAIL (exec-mask) -> R8 615 WIN (zero-row broadcast) ->
// R9 617 / R12 617 NEUTRAL (reg diet; ds_read2 pairing) -> R10 695 FAIL
// (512thr) -> R11 1310 FAIL (VMEM on barrier-locked path).
//
// Model v4: R8/R9/R12 neutrality falsifies "LDS issue-bound" (v3). R10/R11
// show latency sensitivity. Binding constraint = per-step SERIAL chain:
// A-read -> MFMA chain -> acc store -> lgkm drain -> pre read -> VALU/trans
// chain -> barrier, partially hidden at 4 waves/SIMD.
//
// R13 (fifth submission; four rounds lost to infra): ZERO-EXCHANGE LANE
// MAP. C/D layout row=(lane>>4)*4+reg (m89) => place batch row rr at A-row
// 4*rr (A-tile: live slots 0..3 via aoff remap, zero slot 4 unchanged).
// Then lane (rr<<4)|n holds preact[row rr][unit n] in acc[j][0] directly:
// phase-B role (row=lane>>4, unit=wv*16+(lane&15)) needs NO exchange.
// Removes: 3 acc stores + lgkm drain + pre reads + q==0 divergence + ig
// LDS bounce (ig back in register). Ledger 18 -> 13 LDS instrs/wave/step;
// ~250-350 cyc of serial store->drain->read latency cut from the chain.
// Net live-reg delta ~ -1 (acc[j][0] live into phase B, but pbase/pre
// temps freed); acc[j][1..3] die at last MFMA.
// Arithmetic BIT-IDENTICAL (same MFMA sums, same scalar ops, different
// lane): absmax must be exactly 2.441406e-4; any change = indexing bug.
// If neutral -> serial exchange wasn't binding -> R14 = i8 16x16x64
// (A-reads 8->4, Bf 96->24 regs, quantization risk ~1e-2 absmax).
// If regression -> check WRITE_SIZE (acc AGPR liveness through phase B).
__global__ __launch_bounds__(1024)
void ealstm_kernel(const float* __restrict__ x_dyn,  const float* __restrict__ x_stat,
                   const float* __restrict__ W_i,    const float* __restrict__ b_i,
                   const float* __restrict__ W_f,    const float* __restrict__ b_f,
                   const float* __restrict__ W_g,    const float* __restrict__ b_g,
                   const float* __restrict__ W_o,    const float* __restrict__ b_o,
                   const float* __restrict__ W_head, const float* __restrict__ b_head,
                   float* __restrict__ out)
{
    // LDS: 5440 + 4096 + 12288 + 23360 + 432 = 45616 B
    __shared__ __align__(16) unsigned short Abuf[2][AR * SA]; // batch-row slots 0..3 + zero slot 4, double-buffered
    __shared__ __align__(16) float          pre[1024];        // head staging only
    __shared__ __align__(16) unsigned short WxL[G3 * 8];      // per col: Wx[0..4], bias, 0, 0 (bf16)
    __shared__ __align__(16) unsigned short xcA[TS * 4 * 8];  // per (t,row): x[0..4], 1.0, 0, 0 (bf16)
    __shared__ __align__(16) float          xst[BS * NS];

    const int tid  = threadIdx.x;
    const int bid  = blockIdx.x;
    const int b0   = bid * BS;
    const int lane = tid & 63;
    const int wv   = tid >> 6;        // wave 0..15
    const int q    = lane >> 4;       // quad 0..3 = MFMA K-group AND this thread's batch row
    const int n    = lane & 15;       // MFMA col-in-tile = unit-local index
    const int u    = wv * UPW + n;    // owned hidden unit (phase B)

    // ---- init LDS ----
    for (int i = tid; i < 2 * AR * SA / 2; i += 1024)
        ((unsigned int*)Abuf)[i] = 0u;                 // zero both A buffers (h0 = 0; slot 4 stays 0 forever)
    for (int i = tid; i < BS * NS; i += 1024)
        xst[i] = x_stat[(b0 + i / NS) * NS + (i % NS)];
    for (int i = tid; i < TS * BS; i += 1024) {        // x rows, 16B-aligned per (t,row)
        int t = i >> 2, rr = i & 3;
        const float* xp = x_dyn + ((size_t)(b0 + rr) * TS + t) * DDYN;
        unsigned short* dst = &xcA[(unsigned)i * 8];
        #pragma unroll
        for (int d = 0; d < DDYN; d++) dst[d] = f2bf(xp[d]);
        dst[5] = 0x3F80; dst[6] = 0; dst[7] = 0;
    }
    if (tid < G3) {
        int col = tid;
        int gate = col >> 8, hc = col & 255;
        const float* Wg = gate == 0 ? W_f : (gate == 1 ? W_g : W_o);
        const float* bg = gate == 0 ? b_f : (gate == 1 ? b_g : b_o);
        #pragma unroll
        for (int d = 0; d < DDYN; d++) WxL[col * 8 + d] = f2bf(Wg[hc * (DDYN + HID) + d]);
        WxL[col * 8 + 5] = f2bf(bg[hc]);
        WxL[col * 8 + 6] = 0; WxL[col * 8 + 7] = 0;
    }

    // ---- persistent B fragments: 3 tiles x 8 K-chunks x 4 VGPR = 96 regs ----
    short8 Bf[NTILE][8];
    #pragma unroll
    for (int j = 0; j < NTILE; j++) {
        int urow = wv * UPW + n;           // weight row (hidden unit), gate j
        const float* Wg = j == 0 ? W_f : (j == 1 ? W_g : W_o);
        const float* wrow = Wg + urow * (DDYN + HID) + DDYN;   // skip x-part
        #pragma unroll
        for (int c = 0; c < 8; c++) {
            int k0 = c * 32 + q * 8;
            short8 fr;
            #pragma unroll
            for (int e = 0; e < 8; e++) fr[e] = (short)f2bf(wrow[k0 + e]);
            Bf[j][c] = fr;
        }
    }
    __syncthreads();

    // ---- i_gate for this thread's (unit u, row q) — register resident ----
    float ig, cst = 0.f;
    {
        float a = b_i[u];
        for (int s = 0; s < NS; s++)
            a += xst[q * NS + s] * W_i[u * NS + s];
        ig = fsig(a);
    }

    // A-row (lane&15) holds batch row n/4 iff n%4==0 (slots 0..3), else the
    // shared zero slot 4 (LDS same-address broadcast).
    const int aoff = ((n & 3) == 0) ? (n >> 2) * SA : 4 * SA;

    // One LSTM step: PA/PB are compile-time LDS bases after macro expansion.
    // Phase A leaves preact[row q][unit u] of gate j in acc[j][0] — no
    // exchange, no store, no drain, no divergence.
#define STEP(PA, PB, T)                                                        \
    {                                                                          \
        f32x4 acc[NTILE];                                                      \
        _Pragma("unroll")                                                      \
        for (int j = 0; j < NTILE; j++) acc[j] = (f32x4){0.f, 0.f, 0.f, 0.f}; \
        _Pragma("unroll")                                                      \
        for (int c = 0; c < 8; c++) {                                          \
            short8 a = *(const short8*)&(PA)[aoff + c * 32 + q * 8];           \
            _Pragma("unroll")                                                  \
            for (int j = 0; j < NTILE; j++)                                    \
                acc[j] = __builtin_amdgcn_mfma_f32_16x16x32_bf16(              \
                    a, Bf[j][c], acc[j], 0, 0, 0);                             \
            __asm__ volatile("" ::: "memory");                                 \
        }                                                                      \
        {                                                                      \
            short8 xv = *(const short8*)&xcA[(unsigned)((T) * 4 + q) * 8];     \
            short8 wf = *(const short8*)&WxL[(u)        * 8];                  \
            short8 wg = *(const short8*)&WxL[(256 + u)  * 8];                  \
            short8 wo = *(const short8*)&WxL[(512 + u)  * 8];                  \
            float pf = acc[0][0] + bf2f_s(wf[5]);                              \
            float pg = acc[1][0] + bf2f_s(wg[5]);                              \
            float po = acc[2][0] + bf2f_s(wo[5]);                              \
            _Pragma("unroll")                                                  \
            for (int d = 0; d < DDYN; d++) {                                   \
                float xd = bf2f_s(xv[d]);                                      \
                pf += xd * bf2f_s(wf[d]);                                      \
                pg += xd * bf2f_s(wg[d]);                                      \
                po += xd * bf2f_s(wo[d]);                                      \
            }                                                                  \
            float f  = fsig(pf);                                               \
            float g_ = ftanh(pg);                                              \
            float o  = fsig(po);                                               \
            cst = f * cst + ig * g_;                                           \
            float h = o * ftanh(cst);                                          \
            (PB)[q * SA + u] = f2bf(h);                                        \
        }                                                                      \
        __syncthreads();                                                       \
    }

    // ---- time loop, unrolled x2: t=0..363 as 182 pairs, then tail t=364 ----
    {
        unsigned short* const A0 = &Abuf[0][0];
        unsigned short* const A1 = &Abuf[1][0];
        for (int tp = 0; tp < 182; tp++) {
            const int t0 = tp * 2;
            STEP(A0, A1, t0);        // even step: read buf0, write buf1
            STEP(A1, A0, t0 + 1);    // odd  step: read buf1, write buf0
        }
        STEP(A0, A1, 364);           // tail: final h lands in buffer 1
    }
#undef STEP

    // ---- head: out[b] = h . W_head + b_head (TS odd -> final h in buffer 1) ----
    {
        float h = bf2f(Abuf[1][q * SA + u]);
        pre[u * 4 + q] = h * W_head[u];
    }
    __syncthreads();
    if (tid < 64) {
        f32x4 s = *(const f32x4*)&pre[tid * 4];
        #pragma unroll
        for (int k = 1; k < 4; k++) {
            f32x4 v = *(const f32x4*)&pre[(tid + k * 64) * 4];
            #pragma unroll
            for (int rr = 0; rr < BS; rr++) s[rr] += v[rr];
        }
        #pragma unroll
        for (int off = 32; off > 0; off >>= 1)
            #pragma unroll
            for (int rr = 0; rr < BS; rr++) s[rr] += __shfl_down(s[rr], off, 64);
        if (tid == 0) {
            float bh = b_head[0];
            #pragma unroll
            for (int rr = 0; rr < BS; rr++) out[b0 + rr] = s[rr] + bh;
        }
    }
}

extern "C" void kernel_launch(void* const* d_in, const int* in_sizes, int n_in,
                              void* d_out, int out_size, void* d_ws, size_t ws_size,
                              hipStream_t stream) {
    ealstm_kernel<<<256, 1024, 0, stream>>>(
        (const float*)d_in[0],  (const float*)d_in[1],  (const float*)d_in[2],
        (const float*)d_in[3],  (const float*)d_in[4],  (const float*)d_in[5],
        (const float*)d_in[6],  (const float*)d_in[7],  (const float*)d_in[8],
        (const float*)d_in[9],  (const float*)d_in[10], (const float*)d_in[11],
        (float*)d_out);
}